// Round 1
// baseline (8145.141 us; speedup 1.0000x reference)
//
#include <hip/hip_runtime.h>
#include <stdint.h>

// Problem constants (bidirectionalRNN: S=256, B=32, I=H=1024, L=2)
#define SEQ   256
#define BSZ   32
#define HD    1024
#define GD    4096          // 4*H
#define KD    1024
#define MROWS (SEQ*BSZ)     // 8192

typedef unsigned short u16;
typedef __attribute__((ext_vector_type(8))) __bf16 bf8_t;
typedef __attribute__((ext_vector_type(4))) float  f4_t;

__device__ __forceinline__ u16 f2bf(float f) {
  unsigned u = __float_as_uint(f);
  u += 0x7fffu + ((u >> 16) & 1u);      // RNE
  return (u16)(u >> 16);
}
__device__ __forceinline__ float bf2f(u16 s) {
  return __uint_as_float(((unsigned)s) << 16);
}
__device__ __forceinline__ void async_copy16(const void* g, void* l) {
  __builtin_amdgcn_global_load_lds(
      (const __attribute__((address_space(1))) void*)g,
      (__attribute__((address_space(3))) void*)l, 16, 0, 0);
}
__device__ __forceinline__ float sigm(float x) { return 1.0f / (1.0f + __expf(-x)); }
__device__ __forceinline__ float tanh_f(float x) {
  float e = __expf(-2.0f * x);          // inf-safe: x<<0 -> e=inf -> -1
  return 2.0f / (1.0f + e) - 1.0f;
}

// ---------------- fp32 -> bf16 conversion (x4 vectorized) ----------------
__global__ void cvt_f32_bf16(const float* __restrict__ src, u16* __restrict__ dst, int n4) {
  int i = blockIdx.x * blockDim.x + threadIdx.x;
  if (i >= n4) return;
  float4 v = ((const float4*)src)[i];
  ushort4 o;
  o.x = f2bf(v.x); o.y = f2bf(v.y); o.z = f2bf(v.z); o.w = f2bf(v.w);
  ((ushort4*)dst)[i] = o;
}

// ---------------- bf16 GEMM: C[M,N] = A[M,K] @ B[N,K]^T, C in bf16 -------
// m97 structure: 128x128 tile, 4 waves, 4x4 16x16x32 MFMA tiles per wave,
// BK=32, global_load_lds width=16 staging.
__global__ __launch_bounds__(256) void gemm_bt(
    const u16* __restrict__ A, const u16* __restrict__ B, u16* __restrict__ C,
    int M, int N, int K)
{
  __shared__ u16 lA[128 * 32];   // 8 KB
  __shared__ u16 lB[128 * 32];
  const int tid  = threadIdx.x;
  const int wave = tid >> 6, lane = tid & 63;
  const int wr = (wave >> 1) * 64, wc = (wave & 1) * 64;
  const int m0 = blockIdx.x * 128, n0 = blockIdx.y * 128;

  f4_t acc[4][4] = {};

  // staging: 512 16B-chunks per tile; thread t -> chunks t and t+256.
  // chunk c: row=c>>2, kpart=(c&3)*8; LDS ushort offset = c*8 (row-major [128][32]).
  const int r0 = tid >> 2,          kp0 = (tid & 3) * 8;
  const int r1 = (tid + 256) >> 2,  kp1 = (tid & 3) * 8;
  const u16* gA0 = A + (size_t)(m0 + r0) * K + kp0;
  const u16* gA1 = A + (size_t)(m0 + r1) * K + kp1;
  const u16* gB0 = B + (size_t)(n0 + r0) * K + kp0;
  const u16* gB1 = B + (size_t)(n0 + r1) * K + kp1;
  // wave-uniform LDS bases (HW writes base + lane*16)
  u16* lA0 = lA + wave * 512;          u16* lA1 = lA + 2048 + wave * 512;
  u16* lB0 = lB + wave * 512;          u16* lB1 = lB + 2048 + wave * 512;

  const int fr = lane & 15, fk = (lane >> 4) * 8;

  for (int k0 = 0; k0 < K; k0 += 32) {
    async_copy16(gA0 + k0, lA0);
    async_copy16(gA1 + k0, lA1);
    async_copy16(gB0 + k0, lB0);
    async_copy16(gB1 + k0, lB1);
    __syncthreads();                    // drains vmcnt before barrier
    bf8_t af[4], bf[4];
    #pragma unroll
    for (int i = 0; i < 4; i++) af[i] = *(const bf8_t*)&lA[(wr + i * 16 + fr) * 32 + fk];
    #pragma unroll
    for (int i = 0; i < 4; i++) bf[i] = *(const bf8_t*)&lB[(wc + i * 16 + fr) * 32 + fk];
    #pragma unroll
    for (int mi = 0; mi < 4; mi++)
      #pragma unroll
      for (int ni = 0; ni < 4; ni++)
        acc[mi][ni] = __builtin_amdgcn_mfma_f32_16x16x32_bf16(af[mi], bf[ni], acc[mi][ni], 0, 0, 0);
    __syncthreads();
  }
  // epilogue: D[m][n]: n = lane&15, m = (lane>>4)*4 + r
  const int er = (lane >> 4) * 4, ec = lane & 15;
  #pragma unroll
  for (int mi = 0; mi < 4; mi++)
    #pragma unroll
    for (int ni = 0; ni < 4; ni++)
      #pragma unroll
      for (int r = 0; r < 4; r++) {
        int m = m0 + wr + mi * 16 + er + r;
        int n = n0 + wc + ni * 16 + ec;
        C[(size_t)m * N + n] = f2bf(acc[mi][ni][r]);
      }
}

// ---------------- one LSTM time step, both directions --------------------
// grid: (HD/16, 2 dirs), 256 threads (4 waves = gate groups i,f,g,o).
// Block owns h-dims [j0, j0+16); wave w computes gates rows w*1024+j0+[0,16)
// for all 32 batches via 2 MFMA tiles over K=1024 (direct global frag loads).
__global__ __launch_bounds__(256) void lstm_step(
    const u16* __restrict__ whh,    // [2dir][2layer][4096][1024] bf16
    const u16* __restrict__ xg,     // [2dir][8192][4096] bf16 (current layer)
    u16*       __restrict__ hstate, // [2buf][2dir][32][1024] bf16
    float*     __restrict__ cstate, // [2dir][32][1024] f32
    u16*       __restrict__ h0out,  // [2dir][8192][1024] bf16 (layer0 out)
    float*     __restrict__ dout,   // full output buffer
    int layer, int t)
{
  const int tid = threadIdx.x;
  const int w = tid >> 6, lane = tid & 63;
  const int d = blockIdx.y;
  const int j0 = blockIdx.x * 16;
  const int tt = d ? (SEQ - 1 - t) : t;     // original time index processed
  const int rbuf = t & 1, wbuf = rbuf ^ 1;
  const int fr = lane & 15, quad = lane >> 4;
  const int fk = quad * 8;

  const u16* hA = hstate + (size_t)(rbuf * 2 + d) * BSZ * HD;
  const u16* Wr = whh + ((size_t)(d * 2 + layer) * GD + (w * HD + j0 + fr)) * KD;

  f4_t acc0 = {}, acc1 = {};
  #pragma unroll 8
  for (int k = 0; k < KD; k += 32) {
    bf8_t bfrag = *(const bf8_t*)(Wr + k + fk);                       // B[n=fr][k]
    bf8_t a0    = *(const bf8_t*)(hA + (size_t)fr * HD + k + fk);     // batches 0-15
    bf8_t a1    = *(const bf8_t*)(hA + (size_t)(fr + 16) * HD + k + fk); // 16-31
    acc0 = __builtin_amdgcn_mfma_f32_16x16x32_bf16(a0, bfrag, acc0, 0, 0, 0);
    acc1 = __builtin_amdgcn_mfma_f32_16x16x32_bf16(a1, bfrag, acc1, 0, 0, 0);
  }

  // add xg and exchange gate tiles through LDS
  __shared__ float lG[4][32][16];
  const u16* xgp = xg + ((size_t)d * MROWS + (size_t)tt * BSZ) * GD + (w * HD + j0);
  #pragma unroll
  for (int r = 0; r < 4; r++) {
    lG[w][quad * 4 + r][fr]      = acc0[r] + bf2f(xgp[(size_t)(quad * 4 + r) * GD + fr]);
    lG[w][16 + quad * 4 + r][fr] = acc1[r] + bf2f(xgp[(size_t)(16 + quad * 4 + r) * GD + fr]);
  }
  __syncthreads();

  #pragma unroll
  for (int u = 0; u < 2; u++) {
    int cell = tid * 2 + u;           // 512 cells = 32 batches x 16 j
    int b = cell >> 4, j = cell & 15;
    float iv = sigm(lG[0][b][j]);
    float fv = sigm(lG[1][b][j]);
    float gv = tanh_f(lG[2][b][j]);
    float ov = sigm(lG[3][b][j]);
    size_t cidx = ((size_t)d * BSZ + b) * HD + j0 + j;
    float cp = cstate[cidx];
    float cn = fv * cp + iv * gv;
    float hn = ov * tanh_f(cn);
    cstate[cidx] = cn;
    hstate[((size_t)(wbuf * 2 + d) * BSZ + b) * HD + j0 + j] = f2bf(hn);
    if (layer == 0) {
      h0out[((size_t)d * MROWS + (size_t)tt * BSZ + b) * HD + j0 + j] = f2bf(hn);
    } else {
      dout[((size_t)tt * BSZ + b) * (2 * HD) + (size_t)d * HD + j0 + j] = hn;
    }
    // h_last/c_last capture: fwd at final step; bwd at its FIRST step (torch
    // stackedRNN quirk: flipped hs[-1] == state after processing x[S-1]).
    if ((d == 0 && t == SEQ - 1) || (d == 1 && t == 0)) {
      size_t hoff = (size_t)MROWS * 2 * HD + ((size_t)layer * BSZ + b) * (2 * HD)
                  + (size_t)d * HD + j0 + j;
      dout[hoff] = hn;                          // h_all
      dout[hoff + (size_t)2 * BSZ * 2 * HD] = cn;  // c_all (L*B*2H further)
    }
  }
}

// -------------------------------------------------------------------------
extern "C" void kernel_launch(void* const* d_in, const int* in_sizes, int n_in,
                              void* d_out, int out_size, void* d_ws, size_t ws_size,
                              hipStream_t stream) {
  const float* x    = (const float*)d_in[0];
  const float* wihf = (const float*)d_in[1];
  const float* whhf = (const float*)d_in[2];
  const float* wihb = (const float*)d_in[3];
  const float* whhb = (const float*)d_in[4];
  float* out = (float*)d_out;

  const size_t NE = (size_t)MROWS * KD;   // 8388608 elems (x and each weight tensor)
  char* ws = (char*)d_ws;
  u16*   xbf = (u16*)ws;                                   // 16 MB
  u16*   wih = (u16*)(ws + NE * 2);                        // [2dir][2l][4096][1024], 32 MB
  u16*   whh = wih + 2 * NE;                               // 32 MB
  u16*   xg  = whh + 2 * NE;                               // [2dir][8192][4096], 128 MB
  u16*   h0  = xg + (size_t)2 * MROWS * GD;                // [2dir][8192][1024], 32 MB
  u16*   hst = h0 + (size_t)2 * MROWS * HD;                // [2buf][2dir][32][1024], 256 KB
  float* cst = (float*)(hst + (size_t)2 * 2 * BSZ * HD);   // [2dir][32][1024], 256 KB

  // 1) convert inputs to bf16
  const int n4 = (int)(NE / 4);
  const int cg = n4 / 256;
  cvt_f32_bf16<<<cg, 256, 0, stream>>>(x,    xbf,      n4);
  cvt_f32_bf16<<<cg, 256, 0, stream>>>(wihf, wih,      n4);
  cvt_f32_bf16<<<cg, 256, 0, stream>>>(wihb, wih + NE, n4);
  cvt_f32_bf16<<<cg, 256, 0, stream>>>(whhf, whh,      n4);
  cvt_f32_bf16<<<cg, 256, 0, stream>>>(whhb, whh + NE, n4);

  const size_t stateBytes = (size_t)2 * 2 * BSZ * HD * 2 + (size_t)2 * BSZ * HD * 4;
  hipMemsetAsync(hst, 0, stateBytes, stream);

  dim3 gg(MROWS / 128, GD / 128);   // 64 x 32

  // 2) layer-0 input projections
  for (int d = 0; d < 2; d++)
    gemm_bt<<<gg, 256, 0, stream>>>(xbf, wih + (size_t)(d * 2) * GD * KD,
                                    xg + (size_t)d * MROWS * GD, MROWS, GD, KD);
  // 3) layer-0 recurrence
  for (int t = 0; t < SEQ; t++)
    lstm_step<<<dim3(HD / 16, 2), 256, 0, stream>>>(whh, xg, hst, cst, h0, out, 0, t);

  // 4) layer-1 input projections (from layer-0 per-dir outputs)
  for (int d = 0; d < 2; d++)
    gemm_bt<<<gg, 256, 0, stream>>>(h0 + (size_t)d * MROWS * HD,
                                    wih + (size_t)(d * 2 + 1) * GD * KD,
                                    xg + (size_t)d * MROWS * GD, MROWS, GD, KD);
  // 5) layer-1 recurrence (writes final output + captures)
  hipMemsetAsync(hst, 0, stateBytes, stream);
  for (int t = 0; t < SEQ; t++)
    lstm_step<<<dim3(HD / 16, 2), 256, 0, stream>>>(whh, xg, hst, cst, h0, out, 1, t);
}